// Round 3
// baseline (753.863 us; speedup 1.0000x reference)
//
#include <hip/hip_runtime.h>
#include <stdint.h>

#define HID 512
#define THREE_H 1536
#define ADIM 256
#define NVOC 10000
#define TEnc 256
#define TDec 128

typedef float f32x4 __attribute__((ext_vector_type(4)));
typedef __bf16 bf16x8 __attribute__((ext_vector_type(8)));

__device__ __forceinline__ unsigned short f2bf(float f) {
  union { float f; unsigned u; } v; v.f = f;
  unsigned r = v.u + 0x7FFFu + ((v.u >> 16) & 1u);
  return (unsigned short)(r >> 16);
}
__device__ __forceinline__ float sigmoidf_(float x) { return 1.f / (1.f + __expf(-x)); }
__device__ __forceinline__ float tanh_fast(float x) {
  float ax = fabsf(x);
  float e = __expf(ax + ax);
  float t = 1.f - 2.f / (e + 1.f);
  return copysignf(t, x);
}

#define GLDS16(gp, lp)                                                                 \
  __builtin_amdgcn_global_load_lds((const __attribute__((address_space(1))) void*)(gp),\
                                   (__attribute__((address_space(3))) void*)(lp), 16, 0, 0)

// ---------------- fp32 -> bf16 convert (x and y fused) ----------------
__global__ void cvt_xy(const float* __restrict__ x, const float* __restrict__ y,
                       unsigned short* __restrict__ xb, unsigned short* __restrict__ yb) {
  int i = (blockIdx.x * blockDim.x + threadIdx.x) * 4;
  const float* src;
  unsigned short* dst;
  int j;
  if (i < TEnc * HID) { src = x; dst = xb; j = i; }
  else { src = y; dst = yb; j = i - TEnc * HID; }
  float4 v = *(const float4*)(src + j);
  ushort4 o;
  o.x = f2bf(v.x); o.y = f2bf(v.y); o.z = f2bf(v.z); o.w = f2bf(v.w);
  *(ushort4*)(dst + j) = o;
}

// ---------------- generic BT-GEMM: C[M,N] = A[M,K](bf16) * B[N,K]^T(f32->bf16) + bias ----------------
template <int BN, int BK>
__global__ __launch_bounds__(256, 1) void gemm_bt(
    const unsigned short* __restrict__ Abf, const float* __restrict__ B,
    const float* __restrict__ bias, float* __restrict__ C, unsigned short* __restrict__ Cbf,
    int M, int N, int K) {
  constexpr int NF = BN / 16;
  constexpr int B4 = BN * BK / 1024;
  constexpr int AG = BK / 16;
  constexpr int KK = BK / 32;
  extern __shared__ char smem[];
  unsigned short* Al0 = (unsigned short*)smem;
  unsigned short* Al1 = Al0 + 128 * BK;
  unsigned short* Bl0 = Al1 + 128 * BK;
  unsigned short* Bl1 = Bl0 + BN * BK;

  const int tid = threadIdx.x;
  const int lane = tid & 63;
  const int wid = tid >> 6;
  const int m0 = blockIdx.x * 128;
  const int n0 = blockIdx.y * BN;
  const int NT = K / BK;

  float4 breg[B4];
  f32x4 acc[2][NF];
#pragma unroll
  for (int i = 0; i < 2; ++i)
#pragma unroll
    for (int j = 0; j < NF; ++j) acc[i][j] = (f32x4){0.f, 0.f, 0.f, 0.f};

  auto stageA = [&](int t, unsigned short* dst) {
    const unsigned short* Ab = Abf + (size_t)m0 * K + (size_t)t * BK;
#pragma unroll
    for (int g = 0; g < AG; ++g) {
      int elem = g * 2048 + tid * 8;
      int arow = elem / BK;
      int acol = elem - arow * BK;
      GLDS16(Ab + (size_t)arow * K + acol, (char*)dst + g * 4096 + wid * 1024);
    }
  };
  auto loadB = [&](int t) {
    const float* Bb = B + (size_t)t * BK;
#pragma unroll
    for (int p = 0; p < B4; ++p) {
      int e = (p * 256 + tid) * 4;
      int brow = e / BK;
      int bcol = e - brow * BK;
      int grow = n0 + brow;
      if (grow > N - 1) grow = N - 1;
      breg[p] = *(const float4*)(Bb + (size_t)grow * K + bcol);
    }
  };
  auto writeB = [&](unsigned short* dst) {
#pragma unroll
    for (int p = 0; p < B4; ++p) {
      ushort4 o;
      o.x = f2bf(breg[p].x); o.y = f2bf(breg[p].y);
      o.z = f2bf(breg[p].z); o.w = f2bf(breg[p].w);
      *(ushort4*)((char*)dst + (p * 256 + tid) * 8) = o;
    }
  };

  stageA(0, Al0);
  loadB(0);
  for (int t = 0; t < NT; ++t) {
    unsigned short* Ac = (t & 1) ? Al1 : Al0;
    unsigned short* Bc = (t & 1) ? Bl1 : Bl0;
    asm volatile("s_waitcnt vmcnt(0)" ::: "memory");
    writeB(Bc);
    __syncthreads();
    if (t + 1 < NT) {
      stageA(t + 1, (t & 1) ? Al0 : Al1);
      loadB(t + 1);
    }
    const int r0 = lane & 15;
    const int kb = (lane >> 4) * 8;
#pragma unroll
    for (int kk = 0; kk < KK; ++kk) {
      int ko = kk * 32 + kb;
      bf16x8 a0 = *(const bf16x8*)(Ac + (wid * 32 + r0) * BK + ko);
      bf16x8 a1 = *(const bf16x8*)(Ac + (wid * 32 + 16 + r0) * BK + ko);
#pragma unroll
      for (int nf = 0; nf < NF; ++nf) {
        bf16x8 bb = *(const bf16x8*)(Bc + (nf * 16 + r0) * BK + ko);
        acc[0][nf] = __builtin_amdgcn_mfma_f32_16x16x32_bf16(a0, bb, acc[0][nf], 0, 0, 0);
        acc[1][nf] = __builtin_amdgcn_mfma_f32_16x16x32_bf16(a1, bb, acc[1][nf], 0, 0, 0);
      }
    }
  }
  const int cc = lane & 15;
  const int rq = (lane >> 4) * 4;
#pragma unroll
  for (int mi = 0; mi < 2; ++mi) {
    int row = m0 + wid * 32 + mi * 16 + rq;
#pragma unroll
    for (int nf = 0; nf < NF; ++nf) {
      int col = n0 + nf * 16 + cc;
      if (col < N) {
        float bv = bias ? bias[col] : 0.f;
#pragma unroll
        for (int j = 0; j < 4; ++j) {
          float v = acc[mi][nf][j] + bv;
          if (C) C[(size_t)(row + j) * N + col] = v;
          if (Cbf) Cbf[(size_t)(row + j) * N + col] = f2bf(v);
        }
      }
    }
  }
}

// ---------------- encoder GEMM with fused GRU gates (h_prev = 0) ----------------
// Grouped N-tile: WG covers dims j in [n0g, n0g+32) for ALL THREE gates, so the
// same lane holds r/z/n fragments and computes h directly in the epilogue.
__global__ __launch_bounds__(256, 1) void gemm_enc(
    const unsigned short* __restrict__ Abf, const float* __restrict__ Wi,
    const float* __restrict__ bi, const float* __restrict__ bh,
    float* __restrict__ encH, unsigned short* __restrict__ encHbf) {
  constexpr int BN = 96, BK = 128, NF = 6, B4 = 12, AG = 8, KK = 4, K = 512;
  extern __shared__ char smem[];
  unsigned short* Al0 = (unsigned short*)smem;
  unsigned short* Al1 = Al0 + 128 * BK;
  unsigned short* Bl0 = Al1 + 128 * BK;
  unsigned short* Bl1 = Bl0 + BN * BK;

  const int tid = threadIdx.x;
  const int lane = tid & 63;
  const int wid = tid >> 6;
  const int m0 = blockIdx.x * 128;
  const int n0g = blockIdx.y * 32;
  const int NT = K / BK;  // 4

  float4 breg[B4];
  f32x4 acc[2][NF];
#pragma unroll
  for (int i = 0; i < 2; ++i)
#pragma unroll
    for (int j = 0; j < NF; ++j) acc[i][j] = (f32x4){0.f, 0.f, 0.f, 0.f};

  auto stageA = [&](int t, unsigned short* dst) {
    const unsigned short* Ab = Abf + (size_t)m0 * K + (size_t)t * BK;
#pragma unroll
    for (int g = 0; g < AG; ++g) {
      int elem = g * 2048 + tid * 8;
      int arow = elem >> 7;
      int acol = elem & 127;
      GLDS16(Ab + (size_t)arow * K + acol, (char*)dst + g * 4096 + wid * 1024);
    }
  };
  auto loadB = [&](int t) {
    const float* Bb = Wi + (size_t)t * BK;
#pragma unroll
    for (int p = 0; p < B4; ++p) {
      int e = (p * 256 + tid) * 4;
      int brow = e >> 7;
      int bcol = e & 127;
      int grow = (brow >> 5) * HID + n0g + (brow & 31);  // gate-grouped rows
      breg[p] = *(const float4*)(Bb + (size_t)grow * K + bcol);
    }
  };
  auto writeB = [&](unsigned short* dst) {
#pragma unroll
    for (int p = 0; p < B4; ++p) {
      ushort4 o;
      o.x = f2bf(breg[p].x); o.y = f2bf(breg[p].y);
      o.z = f2bf(breg[p].z); o.w = f2bf(breg[p].w);
      *(ushort4*)((char*)dst + (p * 256 + tid) * 8) = o;
    }
  };

  stageA(0, Al0);
  loadB(0);
  for (int t = 0; t < NT; ++t) {
    unsigned short* Ac = (t & 1) ? Al1 : Al0;
    unsigned short* Bc = (t & 1) ? Bl1 : Bl0;
    asm volatile("s_waitcnt vmcnt(0)" ::: "memory");
    writeB(Bc);
    __syncthreads();
    if (t + 1 < NT) {
      stageA(t + 1, (t & 1) ? Al0 : Al1);
      loadB(t + 1);
    }
    const int r0 = lane & 15;
    const int kb = (lane >> 4) * 8;
#pragma unroll
    for (int kk = 0; kk < KK; ++kk) {
      int ko = kk * 32 + kb;
      bf16x8 a0 = *(const bf16x8*)(Ac + (wid * 32 + r0) * BK + ko);
      bf16x8 a1 = *(const bf16x8*)(Ac + (wid * 32 + 16 + r0) * BK + ko);
#pragma unroll
      for (int nf = 0; nf < NF; ++nf) {
        bf16x8 bb = *(const bf16x8*)(Bc + (nf * 16 + r0) * BK + ko);
        acc[0][nf] = __builtin_amdgcn_mfma_f32_16x16x32_bf16(a0, bb, acc[0][nf], 0, 0, 0);
        acc[1][nf] = __builtin_amdgcn_mfma_f32_16x16x32_bf16(a1, bb, acc[1][nf], 0, 0, 0);
      }
    }
  }
  // fused gate epilogue: acc[*][nfj]=r, acc[*][nfj+2]=z, acc[*][nfj+4]=n pre-acts
  const int cc = lane & 15;
  const int rq = (lane >> 4) * 4;
#pragma unroll
  for (int mi = 0; mi < 2; ++mi) {
    int row = m0 + wid * 32 + mi * 16 + rq;
#pragma unroll
    for (int nfj = 0; nfj < 2; ++nfj) {
      int j = n0g + nfj * 16 + cc;
      float br_ = bi[j] + bh[j];
      float bz_ = bi[HID + j] + bh[HID + j];
      float bin_ = bi[2 * HID + j];
      float bhn_ = bh[2 * HID + j];
#pragma unroll
      for (int jj = 0; jj < 4; ++jj) {
        float r = sigmoidf_(acc[mi][nfj][jj] + br_);
        float z = sigmoidf_(acc[mi][nfj + 2][jj] + bz_);
        float n = tanh_fast(acc[mi][nfj + 4][jj] + bin_ + r * bhn_);
        float h = (1.f - z) * n;
        encH[(size_t)(row + jj) * HID + j] = h;
        encHbf[(size_t)(row + jj) * HID + j] = f2bf(h);
      }
    }
  }
}

// ---------------- sequential GRU scan, single-XCD cluster, reg-resident W ----------------
// 256 WGs (1/CU forced via LDS); winner XCD's 32 WGs work. Weights live in
// VGPRs (32 float4/lane, waves 0-2). Wave 3: polls tagged h-words from XCD L2,
// fills swizzle-padded LDS h, prefetches giY[t] during dots, computes gates.
__global__ __launch_bounds__(256, 1) void gru_scan_xcd(
    const float* __restrict__ Whd, const float* __restrict__ bhd,
    const float* __restrict__ giY, const float* __restrict__ h0,
    unsigned long long* __restrict__ hx, unsigned int* __restrict__ cnt,
    unsigned int* __restrict__ winner,
    unsigned short* __restrict__ decSbf, unsigned short* __restrict__ concatbf) {
  extern __shared__ char smem[];
  float* hl = (float*)smem;         // 528 floats, slot = w + ((w>>7)<<2)
  float* dots = hl + 544;           // 48
  volatile int* slot_sh = (volatile int*)(dots + 48);
  const int tid = threadIdx.x;
  const int lane = tid & 63, wid = tid >> 6;

  // ---- election ----
  if (tid == 0) {
    unsigned xcd;
    asm volatile("s_getreg_b32 %0, hwreg(20, 0, 32)" : "=s"(xcd));
    xcd &= 7u;
    unsigned slot = atomicAdd(&cnt[xcd], 1u);
    if (slot == 31u) atomicCAS(winner, 0u, xcd + 1u);
    unsigned win = 0;
    if (slot < 32u) {
      int spin = 0;
      while ((win = __hip_atomic_load(winner, __ATOMIC_RELAXED,
                                      __HIP_MEMORY_SCOPE_AGENT)) == 0u &&
             ++spin < (1 << 20))
        __builtin_amdgcn_s_sleep(2);
    }
    *slot_sh = (slot < 32u && win == xcd + 1u) ? (int)slot : -1;
  }
  __syncthreads();
  const int g = *slot_sh;
  if (g < 0) return;

  const int row16 = lane & 15;
  const int q = lane >> 4;

  // ---- weights into registers: lane holds W[wid*512 + g*16 + row16][q*128 .. +127]
  float4 wreg[32];
  if (wid < 3) {
    const float* wr = Whd + ((size_t)wid * HID + (size_t)g * 16 + row16) * HID + q * 128;
#pragma unroll
    for (int i = 0; i < 32; ++i) wreg[i] = *(const float4*)(wr + i * 4);
  }
  // wave3 gate lanes: preload hidden biases
  float bhr = 0.f, bhz = 0.f, bhn = 0.f;
  if (wid == 3 && lane < 16) {
    int j = g * 16 + lane;
    bhr = bhd[j]; bhz = bhd[HID + j]; bhn = bhd[2 * HID + j];
  }
  // prefill hl with h0 (wave3)
  if (wid == 3) {
#pragma unroll
    for (int k = 0; k < 8; ++k) {
      int w = lane + (k << 6);
      hl[w + ((w >> 7) << 2)] = h0[w];
    }
  }

  volatile unsigned long long* hxv = (volatile unsigned long long*)hx;
  float gir = 0.f, giz = 0.f, gin = 0.f;

  for (int t = 0; t < TDec; ++t) {
    __syncthreads();  // hl(t) ready
    if (wid < 3) {
      const float4* hp = (const float4*)hl;
      const int hb = q * 33;
      float p0 = 0.f, p1 = 0.f, p2 = 0.f, p3 = 0.f;
#pragma unroll
      for (int i = 0; i < 32; i += 4) {
        float4 ha = hp[hb + i], hv = hp[hb + i + 1], hc = hp[hb + i + 2], hd = hp[hb + i + 3];
        float4 wa = wreg[i], wb = wreg[i + 1], wc = wreg[i + 2], wd = wreg[i + 3];
        p0 += wa.x * ha.x + wa.y * ha.y + wa.z * ha.z + wa.w * ha.w;
        p1 += wb.x * hv.x + wb.y * hv.y + wb.z * hv.z + wb.w * hv.w;
        p2 += wc.x * hc.x + wc.y * hc.y + wc.z * hc.z + wc.w * hc.w;
        p3 += wd.x * hd.x + wd.y * hd.y + wd.z * hd.z + wd.w * hd.w;
      }
      float p = (p0 + p1) + (p2 + p3);
      p += __shfl_xor(p, 16);
      p += __shfl_xor(p, 32);
      if (lane < 16) dots[wid * 16 + lane] = p;
    } else if (lane < 16) {
      // prefetch gi[t] — latency hidden under dots
      int j = g * 16 + lane;
      const float* gi = giY + (size_t)t * THREE_H;
      gir = gi[j]; giz = gi[HID + j]; gin = gi[2 * HID + j];
    }
    __syncthreads();  // dots ready
    if (wid == 3) {
      if (lane < 16) {
        int j = g * 16 + lane;
        float hprev = hl[j + ((j >> 7) << 2)];
        float r = sigmoidf_(gir + dots[lane] + bhr);
        float z = sigmoidf_(giz + dots[16 + lane] + bhz);
        float n = tanh_fast(gin + r * (dots[32 + lane] + bhn));
        float hn = (1.f - z) * n + z * hprev;
        hxv[j] = ((unsigned long long)(unsigned)(t + 1) << 32) |
                 (unsigned long long)__float_as_uint(hn);
        unsigned short hb16 = f2bf(hn);
        decSbf[(size_t)t * HID + j] = hb16;
        concatbf[(size_t)t * 2 * HID + HID + j] = hb16;
      }
      if (t < TDec - 1) {
        unsigned need = 0xFFu;
        unsigned long long got[8];
        got[0]=0;got[1]=0;got[2]=0;got[3]=0;got[4]=0;got[5]=0;got[6]=0;got[7]=0;
        int guard = 0;
        while (need && ++guard < (1 << 20)) {
#pragma unroll
          for (int k = 0; k < 8; ++k) {
            if (need & (1u << k)) {
              unsigned long long w = hxv[lane + (k << 6)];
              if ((unsigned)(w >> 32) == (unsigned)(t + 1)) {
                got[k] = w;
                need &= ~(1u << k);
              }
            }
          }
          if (need) __builtin_amdgcn_s_sleep(1);
        }
#pragma unroll
        for (int k = 0; k < 8; ++k) {
          int w = lane + (k << 6);
          hl[w + ((w >> 7) << 2)] = __uint_as_float((unsigned)got[k]);
        }
      }
    }
  }
}

// ---------------- attention scores + softmax + context ----------------
__global__ __launch_bounds__(256) void attn_ctx(const float* __restrict__ encP,
                                                const float* __restrict__ decP,
                                                const float* __restrict__ vattn,
                                                const float* __restrict__ encH,
                                                unsigned short* __restrict__ concatbf) {
  __shared__ float dp[ADIM], vv[ADIM], pl[TEnc];
  __shared__ float red[8];
  const int t = blockIdx.x, tid = threadIdx.x;
  if (tid < 64) {
    *(float4*)(dp + tid * 4) = *(const float4*)(decP + (size_t)t * ADIM + tid * 4);
    *(float4*)(vv + tid * 4) = *(const float4*)(vattn + tid * 4);
  }
  __syncthreads();
  float s = 0.f;
  const float* ep = encP + (size_t)tid * ADIM;
#pragma unroll 4
  for (int a = 0; a < ADIM; a += 4) {
    float4 e4 = *(const float4*)(ep + a);
    s += vv[a] * tanh_fast(e4.x + dp[a]);
    s += vv[a + 1] * tanh_fast(e4.y + dp[a + 1]);
    s += vv[a + 2] * tanh_fast(e4.z + dp[a + 2]);
    s += vv[a + 3] * tanh_fast(e4.w + dp[a + 3]);
  }
  float m = s;
#pragma unroll
  for (int off = 32; off; off >>= 1) m = fmaxf(m, __shfl_xor(m, off));
  if ((tid & 63) == 0) red[tid >> 6] = m;
  __syncthreads();
  m = fmaxf(fmaxf(red[0], red[1]), fmaxf(red[2], red[3]));
  float p = __expf(s - m);
  pl[tid] = p;
  float sum = p;
#pragma unroll
  for (int off = 32; off; off >>= 1) sum += __shfl_xor(sum, off);
  if ((tid & 63) == 0) red[4 + (tid >> 6)] = sum;
  __syncthreads();
  float inv = 1.f / (red[4] + red[5] + red[6] + red[7]);
  float a0 = 0.f, a1 = 0.f;
  for (int e = 0; e < TEnc; ++e) {
    float pe = pl[e];
    a0 += pe * encH[(size_t)e * HID + tid];
    a1 += pe * encH[(size_t)e * HID + tid + 256];
  }
  concatbf[(size_t)t * 2 * HID + tid] = f2bf(a0 * inv);
  concatbf[(size_t)t * 2 * HID + tid + 256] = f2bf(a1 * inv);
}

extern "C" void kernel_launch(void* const* d_in, const int* in_sizes, int n_in,
                              void* d_out, int out_size, void* d_ws, size_t ws_size,
                              hipStream_t stream) {
  const float* x = (const float*)d_in[0];
  const float* y = (const float*)d_in[1];
  const float* Wi_e = (const float*)d_in[2];
  const float* bi_e = (const float*)d_in[4];
  const float* bh_e = (const float*)d_in[5];
  const float* Wi_d = (const float*)d_in[6];
  const float* Wh_d = (const float*)d_in[7];
  const float* bi_d = (const float*)d_in[8];
  const float* bh_d = (const float*)d_in[9];
  const float* Wh_attn = (const float*)d_in[10];
  const float* Ws_attn = (const float*)d_in[11];
  const float* b_attn = (const float*)d_in[12];
  const float* v_attn = (const float*)d_in[13];
  const float* W1 = (const float*)d_in[14];
  const float* b1 = (const float*)d_in[15];
  const float* W2 = (const float*)d_in[16];
  const float* b2 = (const float*)d_in[17];
  float* out = (float*)d_out;

  char* ws = (char*)d_ws;
  size_t off = 0;
  auto alloc = [&](size_t bytes) {
    char* p = ws + off;
    off += (bytes + 255) & ~(size_t)255;
    return p;
  };
  char* ctrl = alloc(8192);
  unsigned long long* hx = (unsigned long long*)ctrl;
  unsigned int* cnt = (unsigned int*)(ctrl + 4096);
  unsigned int* winner = (unsigned int*)(ctrl + 4096 + 128);
  unsigned short* Xbf = (unsigned short*)alloc((size_t)TEnc * HID * 2);
  unsigned short* Ybf = (unsigned short*)alloc((size_t)TDec * HID * 2);
  float* giY = (float*)alloc((size_t)TDec * THREE_H * 4);
  float* encH = (float*)alloc((size_t)TEnc * HID * 4);
  unsigned short* encHbf = (unsigned short*)alloc((size_t)TEnc * HID * 2);
  float* encP = (float*)alloc((size_t)TEnc * ADIM * 4);
  float* decP = (float*)alloc((size_t)TDec * ADIM * 4);
  unsigned short* decSbf = (unsigned short*)alloc((size_t)TDec * HID * 2);
  unsigned short* concatbf = (unsigned short*)alloc((size_t)TDec * 2 * HID * 2);
  unsigned short* out1bf = (unsigned short*)alloc((size_t)TDec * 20000 * 2);

  hipMemsetAsync(ctrl, 0, 8192, stream);

  auto* g32 = gemm_bt<32, 128>;
  auto* g80 = gemm_bt<80, 128>;
  auto* g64 = gemm_bt<64, 160>;
  const int smem32 = (128 + 32) * 128 * 2 * 2;      // 81920
  const int smem80 = (128 + 80) * 128 * 2 * 2;      // 106496
  const int smem64 = (128 + 64) * 160 * 2 * 2;      // 122880
  const int smemEnc = (128 + 96) * 128 * 2 * 2;     // 114688
  const int smemScan = 100608;                      // occupancy forcing (1 WG/CU)
  hipFuncSetAttribute((const void*)g32, hipFuncAttributeMaxDynamicSharedMemorySize, smem32);
  hipFuncSetAttribute((const void*)g80, hipFuncAttributeMaxDynamicSharedMemorySize, smem80);
  hipFuncSetAttribute((const void*)g64, hipFuncAttributeMaxDynamicSharedMemorySize, smem64);
  hipFuncSetAttribute((const void*)gemm_enc, hipFuncAttributeMaxDynamicSharedMemorySize, smemEnc);
  hipFuncSetAttribute((const void*)gru_scan_xcd, hipFuncAttributeMaxDynamicSharedMemorySize, smemScan);

  cvt_xy<<<(TEnc + TDec) * HID / 1024, 256, 0, stream>>>(x, y, Xbf, Ybf);
  // encoder GEMM + fused gates -> encH/encHbf
  gemm_enc<<<dim3(2, 16), 256, smemEnc, stream>>>(Xbf, Wi_e, bi_e, bh_e, encH, encHbf);
  // encP = encH @ Wh_attn^T
  g32<<<dim3(2, 8), 256, smem32, stream>>>(encHbf, Wh_attn, nullptr, encP, nullptr, 256, 256, 512);
  // giY = Ybf @ Wi_d^T + bi_d
  g32<<<dim3(1, 48), 256, smem32, stream>>>(Ybf, Wi_d, bi_d, giY, nullptr, 128, 1536, 512);
  // sequential decoder
  gru_scan_xcd<<<256, 256, smemScan, stream>>>(Wh_d, bh_d, giY, encH + 255 * HID,
                                               hx, cnt, winner, decSbf, concatbf);
  // decP = decS @ Ws_attn^T + b_attn
  g32<<<dim3(1, 8), 256, smem32, stream>>>(decSbf, Ws_attn, b_attn, decP, nullptr, 128, 256, 512);
  attn_ctx<<<TDec, 256, 0, stream>>>(encP, decP, v_attn, encH, concatbf);
  // out1 = concat @ W1^T + b1 (store bf16)
  g80<<<dim3(1, 250), 256, smem80, stream>>>(concatbf, W1, b1, nullptr, out1bf, 128, 20000, 1024);
  // out = out1 @ W2^T + b2 (store f32 to d_out)
  g64<<<dim3(1, 157), 256, smem64, stream>>>(out1bf, W2, b2, out, nullptr, 128, 10000, 20000);
}

// Round 5
// 619.226 us; speedup vs baseline: 1.2174x; 1.2174x over previous
//
#include <hip/hip_runtime.h>
#include <stdint.h>

#define HID 512
#define THREE_H 1536
#define ADIM 256
#define NVOC 10000
#define TEnc 256
#define TDec 128

typedef float f32x4 __attribute__((ext_vector_type(4)));
typedef __bf16 bf16x8 __attribute__((ext_vector_type(8)));

__device__ __forceinline__ unsigned short f2bf(float f) {
  union { float f; unsigned u; } v; v.f = f;
  unsigned r = v.u + 0x7FFFu + ((v.u >> 16) & 1u);
  return (unsigned short)(r >> 16);
}
__device__ __forceinline__ float sigmoidf_(float x) { return 1.f / (1.f + __expf(-x)); }
__device__ __forceinline__ float tanh_fast(float x) {
  float ax = fabsf(x);
  float e = __expf(ax + ax);
  float t = 1.f - 2.f / (e + 1.f);
  return copysignf(t, x);
}

// System-scope exchange (same semantics HIP volatile emits: sc0 sc1).
// r4 ERRATUM: sc0-only polling silently never observes remote stores on
// gfx950 (stale L1 suspected) -> guard expiry, wrong results. sc0 sc1 is
// the r2/r3-proven path (~900cy RTT via memory-side coherence point).
__device__ __forceinline__ void st_u64_sys(unsigned long long* p, unsigned long long v) {
  asm volatile("global_store_dwordx2 %0, %1, off sc0 sc1" :: "v"(p), "v"(v) : "memory");
}
__device__ __forceinline__ unsigned long long ld_u64_sys(const unsigned long long* p) {
  unsigned long long a;
  asm volatile("global_load_dwordx2 %0, %1, off sc0 sc1\n\ts_waitcnt vmcnt(0)"
               : "=&v"(a) : "v"(p) : "memory");
  return a;
}

#define GLDS16(gp, lp)                                                                 \
  __builtin_amdgcn_global_load_lds((const __attribute__((address_space(1))) void*)(gp),\
                                   (__attribute__((address_space(3))) void*)(lp), 16, 0, 0)

// ---------------- fp32 -> bf16 convert (x and y fused) ----------------
__global__ void cvt_xy(const float* __restrict__ x, const float* __restrict__ y,
                       unsigned short* __restrict__ xb, unsigned short* __restrict__ yb) {
  int i = (blockIdx.x * blockDim.x + threadIdx.x) * 4;
  const float* src;
  unsigned short* dst;
  int j;
  if (i < TEnc * HID) { src = x; dst = xb; j = i; }
  else { src = y; dst = yb; j = i - TEnc * HID; }
  float4 v = *(const float4*)(src + j);
  ushort4 o;
  o.x = f2bf(v.x); o.y = f2bf(v.y); o.z = f2bf(v.z); o.w = f2bf(v.w);
  *(ushort4*)(dst + j) = o;
}

// ---------------- BT-GEMM: C[M,N] = A[M,K](bf16) * B[N,K]^T(f32->bf16) + bias ----------------
template <int BN, int BK>
__global__ __launch_bounds__(256, 1) void gemm_bt(
    const unsigned short* __restrict__ Abf, const float* __restrict__ B,
    const float* __restrict__ bias, float* __restrict__ C, unsigned short* __restrict__ Cbf,
    int M, int N, int K) {
  constexpr int NF = BN / 16;
  constexpr int B4 = BN * BK / 1024;
  constexpr int AG = BK / 16;
  constexpr int KK = BK / 32;
  extern __shared__ char smem[];
  unsigned short* Al0 = (unsigned short*)smem;
  unsigned short* Al1 = Al0 + 128 * BK;
  unsigned short* Bl0 = Al1 + 128 * BK;
  unsigned short* Bl1 = Bl0 + BN * BK;

  const int tid = threadIdx.x;
  const int lane = tid & 63;
  const int wid = tid >> 6;
  const int m0 = blockIdx.x * 128;
  const int n0 = blockIdx.y * BN;
  const int NT = K / BK;

  float4 breg[B4];
  f32x4 acc[2][NF];
#pragma unroll
  for (int i = 0; i < 2; ++i)
#pragma unroll
    for (int j = 0; j < NF; ++j) acc[i][j] = (f32x4){0.f, 0.f, 0.f, 0.f};

  auto stageA = [&](int t, unsigned short* dst) {
    const unsigned short* Ab = Abf + (size_t)m0 * K + (size_t)t * BK;
#pragma unroll
    for (int g = 0; g < AG; ++g) {
      int elem = g * 2048 + tid * 8;
      int arow = elem / BK;
      int acol = elem - arow * BK;
      GLDS16(Ab + (size_t)arow * K + acol, (char*)dst + g * 4096 + wid * 1024);
    }
  };
  auto loadB = [&](int t) {
    const float* Bb = B + (size_t)t * BK;
#pragma unroll
    for (int p = 0; p < B4; ++p) {
      int e = (p * 256 + tid) * 4;
      int brow = e / BK;
      int bcol = e - brow * BK;
      int grow = n0 + brow;
      if (grow > N - 1) grow = N - 1;
      breg[p] = *(const float4*)(Bb + (size_t)grow * K + bcol);
    }
  };
  auto writeB = [&](unsigned short* dst) {
#pragma unroll
    for (int p = 0; p < B4; ++p) {
      ushort4 o;
      o.x = f2bf(breg[p].x); o.y = f2bf(breg[p].y);
      o.z = f2bf(breg[p].z); o.w = f2bf(breg[p].w);
      *(ushort4*)((char*)dst + (p * 256 + tid) * 8) = o;
    }
  };

  stageA(0, Al0);
  loadB(0);
  for (int t = 0; t < NT; ++t) {
    unsigned short* Ac = (t & 1) ? Al1 : Al0;
    unsigned short* Bc = (t & 1) ? Bl1 : Bl0;
    asm volatile("s_waitcnt vmcnt(0)" ::: "memory");
    writeB(Bc);
    __syncthreads();
    if (t + 1 < NT) {
      stageA(t + 1, (t & 1) ? Al0 : Al1);
      loadB(t + 1);
    }
    const int r0 = lane & 15;
    const int kb = (lane >> 4) * 8;
#pragma unroll
    for (int kk = 0; kk < KK; ++kk) {
      int ko = kk * 32 + kb;
      bf16x8 a0 = *(const bf16x8*)(Ac + (wid * 32 + r0) * BK + ko);
      bf16x8 a1 = *(const bf16x8*)(Ac + (wid * 32 + 16 + r0) * BK + ko);
#pragma unroll
      for (int nf = 0; nf < NF; ++nf) {
        bf16x8 bb = *(const bf16x8*)(Bc + (nf * 16 + r0) * BK + ko);
        acc[0][nf] = __builtin_amdgcn_mfma_f32_16x16x32_bf16(a0, bb, acc[0][nf], 0, 0, 0);
        acc[1][nf] = __builtin_amdgcn_mfma_f32_16x16x32_bf16(a1, bb, acc[1][nf], 0, 0, 0);
      }
    }
  }
  const int cc = lane & 15;
  const int rq = (lane >> 4) * 4;
#pragma unroll
  for (int mi = 0; mi < 2; ++mi) {
    int row = m0 + wid * 32 + mi * 16 + rq;
#pragma unroll
    for (int nf = 0; nf < NF; ++nf) {
      int col = n0 + nf * 16 + cc;
      if (col < N) {
        float bv = bias ? bias[col] : 0.f;
#pragma unroll
        for (int j = 0; j < 4; ++j) {
          float v = acc[mi][nf][j] + bv;
          if (C) C[(size_t)(row + j) * N + col] = v;
          if (Cbf) Cbf[(size_t)(row + j) * N + col] = f2bf(v);
        }
      }
    }
  }
}

// ---------------- BB-GEMM: C[M,N] = A[M,K](bf16) * B[N,K]^T(bf16) + bias, f32 out ----------------
template <int BN, int BK>
__global__ __launch_bounds__(256, 1) void gemm_bb(
    const unsigned short* __restrict__ Abf, const unsigned short* __restrict__ Bbf,
    const float* __restrict__ bias, float* __restrict__ C, int M, int N, int K) {
  constexpr int NF = BN / 16;
  constexpr int AG = 128 * BK / 2048;
  constexpr int BG = BN * BK / 2048;
  constexpr int KK = BK / 32;
  extern __shared__ char smem[];
  unsigned short* Al0 = (unsigned short*)smem;
  unsigned short* Al1 = Al0 + 128 * BK;
  unsigned short* Bl0 = Al1 + 128 * BK;
  unsigned short* Bl1 = Bl0 + BN * BK;

  const int tid = threadIdx.x;
  const int lane = tid & 63;
  const int wid = tid >> 6;
  const int m0 = blockIdx.x * 128;
  const int n0 = blockIdx.y * BN;
  const int NT = K / BK;

  f32x4 acc[2][NF];
#pragma unroll
  for (int i = 0; i < 2; ++i)
#pragma unroll
    for (int j = 0; j < NF; ++j) acc[i][j] = (f32x4){0.f, 0.f, 0.f, 0.f};

  auto stage = [&](int t, unsigned short* Ad, unsigned short* Bd) {
    const unsigned short* Ab = Abf + (size_t)m0 * K + (size_t)t * BK;
#pragma unroll
    for (int g = 0; g < AG; ++g) {
      int elem = g * 2048 + tid * 8;
      int arow = elem / BK;
      int acol = elem - arow * BK;
      GLDS16(Ab + (size_t)arow * K + acol, (char*)Ad + g * 4096 + wid * 1024);
    }
    const unsigned short* Bb = Bbf + (size_t)t * BK;
#pragma unroll
    for (int g = 0; g < BG; ++g) {
      int elem = g * 2048 + tid * 8;
      int brow = elem / BK;
      int bcol = elem - brow * BK;
      int grow = n0 + brow;
      if (grow > N - 1) grow = N - 1;
      GLDS16(Bb + (size_t)grow * K + bcol, (char*)Bd + g * 4096 + wid * 1024);
    }
  };

  stage(0, Al0, Bl0);
  for (int t = 0; t < NT; ++t) {
    unsigned short* Ac = (t & 1) ? Al1 : Al0;
    unsigned short* Bc = (t & 1) ? Bl1 : Bl0;
    asm volatile("s_waitcnt vmcnt(0)" ::: "memory");
    __syncthreads();
    if (t + 1 < NT) stage(t + 1, (t & 1) ? Al0 : Al1, (t & 1) ? Bl0 : Bl1);
    const int r0 = lane & 15;
    const int kb = (lane >> 4) * 8;
#pragma unroll
    for (int kk = 0; kk < KK; ++kk) {
      int ko = kk * 32 + kb;
      bf16x8 a0 = *(const bf16x8*)(Ac + (wid * 32 + r0) * BK + ko);
      bf16x8 a1 = *(const bf16x8*)(Ac + (wid * 32 + 16 + r0) * BK + ko);
#pragma unroll
      for (int nf = 0; nf < NF; ++nf) {
        bf16x8 bb = *(const bf16x8*)(Bc + (nf * 16 + r0) * BK + ko);
        acc[0][nf] = __builtin_amdgcn_mfma_f32_16x16x32_bf16(a0, bb, acc[0][nf], 0, 0, 0);
        acc[1][nf] = __builtin_amdgcn_mfma_f32_16x16x32_bf16(a1, bb, acc[1][nf], 0, 0, 0);
      }
    }
  }
  const int cc = lane & 15;
  const int rq = (lane >> 4) * 4;
#pragma unroll
  for (int mi = 0; mi < 2; ++mi) {
    int row = m0 + wid * 32 + mi * 16 + rq;
#pragma unroll
    for (int nf = 0; nf < NF; ++nf) {
      int col = n0 + nf * 16 + cc;
      if (col < N) {
        float bv = bias[col];
#pragma unroll
        for (int j = 0; j < 4; ++j)
          C[(size_t)(row + j) * N + col] = acc[mi][nf][j] + bv;
      }
    }
  }
}

// ---------------- encoder GEMM with fused GRU gates (h_prev = 0) ----------------
__global__ __launch_bounds__(256, 1) void gemm_enc(
    const unsigned short* __restrict__ Abf, const float* __restrict__ Wi,
    const float* __restrict__ bi, const float* __restrict__ bh,
    float* __restrict__ encH, unsigned short* __restrict__ encHbf) {
  constexpr int BN = 96, BK = 128, NF = 6, B4 = 12, AG = 8, KK = 4, K = 512;
  extern __shared__ char smem[];
  unsigned short* Al0 = (unsigned short*)smem;
  unsigned short* Al1 = Al0 + 128 * BK;
  unsigned short* Bl0 = Al1 + 128 * BK;
  unsigned short* Bl1 = Bl0 + BN * BK;

  const int tid = threadIdx.x;
  const int lane = tid & 63;
  const int wid = tid >> 6;
  const int m0 = blockIdx.x * 128;
  const int n0g = blockIdx.y * 32;
  const int NT = K / BK;

  float4 breg[B4];
  f32x4 acc[2][NF];
#pragma unroll
  for (int i = 0; i < 2; ++i)
#pragma unroll
    for (int j = 0; j < NF; ++j) acc[i][j] = (f32x4){0.f, 0.f, 0.f, 0.f};

  auto stageA = [&](int t, unsigned short* dst) {
    const unsigned short* Ab = Abf + (size_t)m0 * K + (size_t)t * BK;
#pragma unroll
    for (int g = 0; g < AG; ++g) {
      int elem = g * 2048 + tid * 8;
      int arow = elem >> 7;
      int acol = elem & 127;
      GLDS16(Ab + (size_t)arow * K + acol, (char*)dst + g * 4096 + wid * 1024);
    }
  };
  auto loadB = [&](int t) {
    const float* Bb = Wi + (size_t)t * BK;
#pragma unroll
    for (int p = 0; p < B4; ++p) {
      int e = (p * 256 + tid) * 4;
      int brow = e >> 7;
      int bcol = e & 127;
      int grow = (brow >> 5) * HID + n0g + (brow & 31);
      breg[p] = *(const float4*)(Bb + (size_t)grow * K + bcol);
    }
  };
  auto writeB = [&](unsigned short* dst) {
#pragma unroll
    for (int p = 0; p < B4; ++p) {
      ushort4 o;
      o.x = f2bf(breg[p].x); o.y = f2bf(breg[p].y);
      o.z = f2bf(breg[p].z); o.w = f2bf(breg[p].w);
      *(ushort4*)((char*)dst + (p * 256 + tid) * 8) = o;
    }
  };

  stageA(0, Al0);
  loadB(0);
  for (int t = 0; t < NT; ++t) {
    unsigned short* Ac = (t & 1) ? Al1 : Al0;
    unsigned short* Bc = (t & 1) ? Bl1 : Bl0;
    asm volatile("s_waitcnt vmcnt(0)" ::: "memory");
    writeB(Bc);
    __syncthreads();
    if (t + 1 < NT) {
      stageA(t + 1, (t & 1) ? Al0 : Al1);
      loadB(t + 1);
    }
    const int r0 = lane & 15;
    const int kb = (lane >> 4) * 8;
#pragma unroll
    for (int kk = 0; kk < KK; ++kk) {
      int ko = kk * 32 + kb;
      bf16x8 a0 = *(const bf16x8*)(Ac + (wid * 32 + r0) * BK + ko);
      bf16x8 a1 = *(const bf16x8*)(Ac + (wid * 32 + 16 + r0) * BK + ko);
#pragma unroll
      for (int nf = 0; nf < NF; ++nf) {
        bf16x8 bb = *(const bf16x8*)(Bc + (nf * 16 + r0) * BK + ko);
        acc[0][nf] = __builtin_amdgcn_mfma_f32_16x16x32_bf16(a0, bb, acc[0][nf], 0, 0, 0);
        acc[1][nf] = __builtin_amdgcn_mfma_f32_16x16x32_bf16(a1, bb, acc[1][nf], 0, 0, 0);
      }
    }
  }
  const int cc = lane & 15;
  const int rq = (lane >> 4) * 4;
#pragma unroll
  for (int mi = 0; mi < 2; ++mi) {
    int row = m0 + wid * 32 + mi * 16 + rq;
#pragma unroll
    for (int nfj = 0; nfj < 2; ++nfj) {
      int j = n0g + nfj * 16 + cc;
      float br_ = bi[j] + bh[j];
      float bz_ = bi[HID + j] + bh[HID + j];
      float bin_ = bi[2 * HID + j];
      float bhn_ = bh[2 * HID + j];
#pragma unroll
      for (int jj = 0; jj < 4; ++jj) {
        float r = sigmoidf_(acc[mi][nfj][jj] + br_);
        float z = sigmoidf_(acc[mi][nfj + 2][jj] + bz_);
        float n = tanh_fast(acc[mi][nfj + 4][jj] + bin_ + r * bhn_);
        float h = (1.f - z) * n;
        encH[(size_t)(row + jj) * HID + j] = h;
        encHbf[(size_t)(row + jj) * HID + j] = f2bf(h);
      }
    }
  }
}

// ---------------- sequential GRU scan + fused W2 conversion ----------------
// 256 WGs (1/CU via LDS). Winner XCD's 32 WGs run the scan (proven system-scope
// tagged-word exchange, 2 bf16 dims packed per u64 -> 256 words, 1 poll/thread,
// recurrence kept fp32 in per-lane hreg). The other 224 WGs convert W2 fp32->bf16
// (1.2 GB of HBM traffic) UNDER the scan's latency-bound wait.
__global__ __launch_bounds__(256, 1) void gru_scan_fused(
    const float* __restrict__ Whd, const float* __restrict__ bhd,
    const float* __restrict__ giY, const float* __restrict__ h0,
    const float* __restrict__ W2, unsigned short* __restrict__ W2bf,
    unsigned long long* __restrict__ hx, unsigned int* __restrict__ cnt,
    unsigned int* __restrict__ winner,
    unsigned short* __restrict__ decSbf, unsigned short* __restrict__ concatbf) {
  extern __shared__ char smem[];
  float* hl = (float*)smem;         // 528 used floats, word w -> slot w + ((w>>7)<<2)
  float* dots = hl + 544;           // 48
  volatile int* slot_sh = (volatile int*)(dots + 48);
  const int tid = threadIdx.x;
  const int lane = tid & 63, wid = tid >> 6;

  // ---- election ----
  if (tid == 0) {
    unsigned xcd;
    asm volatile("s_getreg_b32 %0, hwreg(20, 0, 32)" : "=s"(xcd));
    xcd &= 7u;
    unsigned slot = atomicAdd(&cnt[xcd], 1u);
    if (slot == 31u) atomicCAS(winner, 0u, xcd + 1u);
    unsigned win = 0;
    if (slot < 32u) {
      int spin = 0;
      while ((win = __hip_atomic_load(winner, __ATOMIC_RELAXED,
                                      __HIP_MEMORY_SCOPE_AGENT)) == 0u &&
             ++spin < (1 << 20))
        __builtin_amdgcn_s_sleep(2);
    }
    *slot_sh = (slot < 32u && win == xcd + 1u) ? (int)slot : -1;
  }
  __syncthreads();
  const int g = *slot_sh;

  if (g < 0) {
    // ---- converter: W2 fp32 -> bf16, grid-stride over 224 WGs ----
    if (!W2bf) return;
    if (tid == 0) *(volatile unsigned*)hl = atomicAdd(&cnt[8], 1u);
    __syncthreads();
    const unsigned cs = *(volatile unsigned*)hl;
    const size_t NW2 = (size_t)NVOC * 20000;
    const size_t stride = (size_t)224 * 256 * 4;
    for (size_t i = ((size_t)cs * 256 + tid) * 4; i < NW2; i += stride) {
      float4 v = *(const float4*)(W2 + i);
      ushort4 o;
      o.x = f2bf(v.x); o.y = f2bf(v.y); o.z = f2bf(v.z); o.w = f2bf(v.w);
      *(ushort4*)(W2bf + i) = o;
    }
    return;
  }

  // ---- worker ----
  const int row16 = lane & 15;
  const int q = lane >> 4;
  float4 wreg[32];
  {
    int wrow = (wid < 3) ? wid : 0;
    const float* wr = Whd + ((size_t)wrow * HID + (size_t)g * 16 + row16) * HID + q * 128;
#pragma unroll
    for (int i = 0; i < 32; ++i) wreg[i] = *(const float4*)(wr + i * 4);
  }
  float bhr = 0.f, bhz = 0.f, bhn = 0.f, hreg = 0.f;
  if (wid == 3 && lane < 16) {
    int jj = g * 16 + lane;
    bhr = bhd[jj]; bhz = bhd[HID + jj]; bhn = bhd[2 * HID + jj];
    hreg = h0[jj];  // own-dim recurrent state stays fp32 in-register
  }
  {
    int w0 = tid * 2, w1 = tid * 2 + 1;
    hl[w0 + ((w0 >> 7) << 2)] = h0[w0];
    hl[w1 + ((w1 >> 7) << 2)] = h0[w1];
  }
  __syncthreads();

  for (int t = 0; t < TDec; ++t) {
    float gir = 0.f, giz = 0.f, gin = 0.f;
    if (wid < 3) {
      const float4* hp = (const float4*)hl;
      const int hb = q * 33;
      float p0 = 0.f, p1 = 0.f, p2 = 0.f, p3 = 0.f;
#pragma unroll
      for (int i = 0; i < 32; i += 4) {
        float4 ha = hp[hb + i], hv = hp[hb + i + 1], hc = hp[hb + i + 2], hd = hp[hb + i + 3];
        float4 wa = wreg[i], wb = wreg[i + 1], wc = wreg[i + 2], wd = wreg[i + 3];
        p0 += wa.x * ha.x + wa.y * ha.y + wa.z * ha.z + wa.w * ha.w;
        p1 += wb.x * hv.x + wb.y * hv.y + wb.z * hv.z + wb.w * hv.w;
        p2 += wc.x * hc.x + wc.y * hc.y + wc.z * hc.z + wc.w * hc.w;
        p3 += wd.x * hd.x + wd.y * hd.y + wd.z * hd.z + wd.w * hd.w;
      }
      float p = (p0 + p1) + (p2 + p3);
      p += __shfl_xor(p, 16);
      p += __shfl_xor(p, 32);
      if (lane < 16) dots[wid * 16 + lane] = p;
    } else if (lane < 16) {
      int jj = g * 16 + lane;
      const float* gi = giY + (size_t)t * THREE_H;
      gir = gi[jj]; giz = gi[HID + jj]; gin = gi[2 * HID + jj];  // hidden under dots
    }
    __syncthreads();  // dots ready; hl(t) reads done
    unsigned long long* hxB = hx + (size_t)(t & 1) * 256;
    if (wid == 3 && lane < 16) {
      int jj = g * 16 + lane;
      float r = sigmoidf_(gir + dots[lane] + bhr);
      float z = sigmoidf_(giz + dots[16 + lane] + bhz);
      float n = tanh_fast(gin + r * (dots[32 + lane] + bhn));
      float hn = (1.f - z) * n + z * hreg;
      hreg = hn;
      unsigned short hb16 = f2bf(hn);
      unsigned short hb_up = (unsigned short)__shfl_xor((int)hb16, 1);
      if ((lane & 1) == 0) {
        unsigned long long w = ((unsigned long long)(unsigned)(t + 1) << 32) |
                               ((unsigned)hb_up << 16) | (unsigned)hb16;
        st_u64_sys(hxB + g * 8 + (lane >> 1), w);
      }
      decSbf[(size_t)t * HID + jj] = hb16;
      concatbf[(size_t)t * 2 * HID + HID + jj] = hb16;
    }
    if (t == TDec - 1) break;
    // every thread polls exactly one tagged word
    {
      const unsigned long long* p0 = hxB + tid;
      const unsigned tag = (unsigned)(t + 1);
      unsigned long long v;
      int guard = 0;
      do { v = ld_u64_sys(p0); } while ((unsigned)(v >> 32) != tag && ++guard < (1 << 20));
      int w0 = tid * 2, w1 = tid * 2 + 1;
      hl[w0 + ((w0 >> 7) << 2)] = __uint_as_float(((unsigned)v & 0xFFFFu) << 16);
      hl[w1 + ((w1 >> 7) << 2)] = __uint_as_float((((unsigned)v >> 16) & 0xFFFFu) << 16);
    }
    __syncthreads();
  }
}

// ---------------- attention scores + softmax + context ----------------
__global__ __launch_bounds__(256) void attn_ctx(const float* __restrict__ encP,
                                                const float* __restrict__ decP,
                                                const float* __restrict__ vattn,
                                                const float* __restrict__ encH,
                                                unsigned short* __restrict__ concatbf) {
  __shared__ float dp[ADIM], vv[ADIM], pl[TEnc];
  __shared__ float red[8];
  const int t = blockIdx.x, tid = threadIdx.x;
  if (tid < 64) {
    *(float4*)(dp + tid * 4) = *(const float4*)(decP + (size_t)t * ADIM + tid * 4);
    *(float4*)(vv + tid * 4) = *(const float4*)(vattn + tid * 4);
  }
  __syncthreads();
  float s = 0.f;
  const float* ep = encP + (size_t)tid * ADIM;
#pragma unroll 4
  for (int a = 0; a < ADIM; a += 4) {
    float4 e4 = *(const float4*)(ep + a);
    s += vv[a] * tanh_fast(e4.x + dp[a]);
    s += vv[a + 1] * tanh_fast(e4.y + dp[a + 1]);
    s += vv[a + 2] * tanh_fast(e4.z + dp[a + 2]);
    s += vv[a + 3] * tanh_fast(e4.w + dp[a + 3]);
  }
  float m = s;
#pragma unroll
  for (int off = 32; off; off >>= 1) m = fmaxf(m, __shfl_xor(m, off));
  if ((tid & 63) == 0) red[tid >> 6] = m;
  __syncthreads();
  m = fmaxf(fmaxf(red[0], red[1]), fmaxf(red[2], red[3]));
  float p = __expf(s - m);
  pl[tid] = p;
  float sum = p;
#pragma unroll
  for (int off = 32; off; off >>= 1) sum += __shfl_xor(sum, off);
  if ((tid & 63) == 0) red[4 + (tid >> 6)] = sum;
  __syncthreads();
  float inv = 1.f / (red[4] + red[5] + red[6] + red[7]);
  float a0 = 0.f, a1 = 0.f;
  for (int e = 0; e < TEnc; ++e) {
    float pe = pl[e];
    a0 += pe * encH[(size_t)e * HID + tid];
    a1 += pe * encH[(size_t)e * HID + tid + 256];
  }
  concatbf[(size_t)t * 2 * HID + tid] = f2bf(a0 * inv);
  concatbf[(size_t)t * 2 * HID + tid + 256] = f2bf(a1 * inv);
}

extern "C" void kernel_launch(void* const* d_in, const int* in_sizes, int n_in,
                              void* d_out, int out_size, void* d_ws, size_t ws_size,
                              hipStream_t stream) {
  const float* x = (const float*)d_in[0];
  const float* y = (const float*)d_in[1];
  const float* Wi_e = (const float*)d_in[2];
  const float* bi_e = (const float*)d_in[4];
  const float* bh_e = (const float*)d_in[5];
  const float* Wi_d = (const float*)d_in[6];
  const float* Wh_d = (const float*)d_in[7];
  const float* bi_d = (const float*)d_in[8];
  const float* bh_d = (const float*)d_in[9];
  const float* Wh_attn = (const float*)d_in[10];
  const float* Ws_attn = (const float*)d_in[11];
  const float* b_attn = (const float*)d_in[12];
  const float* v_attn = (const float*)d_in[13];
  const float* W1 = (const float*)d_in[14];
  const float* b1 = (const float*)d_in[15];
  const float* W2 = (const float*)d_in[16];
  const float* b2 = (const float*)d_in[17];
  float* out = (float*)d_out;

  char* ws = (char*)d_ws;
  size_t off = 0;
  auto alloc = [&](size_t bytes) {
    char* p = ws + off;
    off += (bytes + 255) & ~(size_t)255;
    return p;
  };
  char* ctrl = alloc(8192);
  unsigned long long* hx = (unsigned long long*)ctrl;          // 2*256*8 = 4096
  unsigned int* cnt = (unsigned int*)(ctrl + 4096);            // 16 words (xcd 0-7, cvt at 8)
  unsigned int* winner = (unsigned int*)(ctrl + 4096 + 128);
  unsigned short* Xbf = (unsigned short*)alloc((size_t)TEnc * HID * 2);
  unsigned short* Ybf = (unsigned short*)alloc((size_t)TDec * HID * 2);
  float* giY = (float*)alloc((size_t)TDec * THREE_H * 4);
  float* encH = (float*)alloc((size_t)TEnc * HID * 4);
  unsigned short* encHbf = (unsigned short*)alloc((size_t)TEnc * HID * 2);
  float* encP = (float*)alloc((size_t)TEnc * ADIM * 4);
  float* decP = (float*)alloc((size_t)TDec * ADIM * 4);
  unsigned short* decSbf = (unsigned short*)alloc((size_t)TDec * HID * 2);
  unsigned short* concatbf = (unsigned short*)alloc((size_t)TDec * 2 * HID * 2);
  unsigned short* out1bf = (unsigned short*)alloc((size_t)TDec * 20000 * 2);
  // W2bf (400 MB) only if the workspace can hold it
  unsigned short* W2bf = nullptr;
  {
    size_t w2_bytes = (size_t)NVOC * 20000 * 2;
    if (ws_size >= off + w2_bytes + 256) W2bf = (unsigned short*)alloc(w2_bytes);
  }

  hipMemsetAsync(ctrl, 0, 8192, stream);

  auto* g32 = gemm_bt<32, 128>;
  auto* g80 = gemm_bt<80, 128>;
  auto* g64 = gemm_bt<64, 160>;
  auto* gbb = gemm_bb<64, 160>;
  const int smem32 = (128 + 32) * 128 * 2 * 2;      // 81920
  const int smem80 = (128 + 80) * 128 * 2 * 2;      // 106496
  const int smem64 = (128 + 64) * 160 * 2 * 2;      // 122880
  const int smemBB = (128 + 64) * 160 * 2 * 2;      // 122880
  const int smemEnc = (128 + 96) * 128 * 2 * 2;     // 114688
  const int smemScan = 100608;                      // forces 1 WG/CU
  hipFuncSetAttribute((const void*)g32, hipFuncAttributeMaxDynamicSharedMemorySize, smem32);
  hipFuncSetAttribute((const void*)g80, hipFuncAttributeMaxDynamicSharedMemorySize, smem80);
  hipFuncSetAttribute((const void*)g64, hipFuncAttributeMaxDynamicSharedMemorySize, smem64);
  hipFuncSetAttribute((const void*)gbb, hipFuncAttributeMaxDynamicSharedMemorySize, smemBB);
  hipFuncSetAttribute((const void*)gemm_enc, hipFuncAttributeMaxDynamicSharedMemorySize, smemEnc);
  hipFuncSetAttribute((const void*)gru_scan_fused, hipFuncAttributeMaxDynamicSharedMemorySize, smemScan);

  cvt_xy<<<(TEnc + TDec) * HID / 1024, 256, 0, stream>>>(x, y, Xbf, Ybf);
  // encoder GEMM + fused gates
  gemm_enc<<<dim3(2, 16), 256, smemEnc, stream>>>(Xbf, Wi_e, bi_e, bh_e, encH, encHbf);
  // encP = encH @ Wh_attn^T
  g32<<<dim3(2, 8), 256, smem32, stream>>>(encHbf, Wh_attn, nullptr, encP, nullptr, 256, 256, 512);
  // giY = Ybf @ Wi_d^T + bi_d
  g32<<<dim3(1, 48), 256, smem32, stream>>>(Ybf, Wi_d, bi_d, giY, nullptr, 128, 1536, 512);
  // sequential decoder scan + fused W2 conversion on idle CUs
  gru_scan_fused<<<256, 256, smemScan, stream>>>(Wh_d, bh_d, giY, encH + 255 * HID,
                                                 W2, W2bf, hx, cnt, winner, decSbf, concatbf);
  // decP = decS @ Ws_attn^T + b_attn
  g32<<<dim3(1, 8), 256, smem32, stream>>>(decSbf, Ws_attn, b_attn, decP, nullptr, 128, 256, 512);
  attn_ctx<<<TDec, 256, 0, stream>>>(encP, decP, v_attn, encH, concatbf);
  // out1 = concat @ W1^T + b1 (store bf16)
  g80<<<dim3(1, 250), 256, smem80, stream>>>(concatbf, W1, b1, nullptr, out1bf, 128, 20000, 1024);
  // out = out1 @ W2^T + b2
  if (W2bf) {
    gbb<<<dim3(1, 157), 256, smemBB, stream>>>(out1bf, W2bf, b2, out, 128, NVOC, 20000);
  } else {
    g64<<<dim3(1, 157), 256, smem64, stream>>>(out1bf, W2, b2, out, nullptr, 128, NVOC, 20000);
  }
}

// Round 6
// 601.106 us; speedup vs baseline: 1.2541x; 1.0301x over previous
//
#include <hip/hip_runtime.h>
#include <stdint.h>

#define HID 512
#define THREE_H 1536
#define ADIM 256
#define NVOC 10000
#define TEnc 256
#define TDec 128

typedef float f32x4 __attribute__((ext_vector_type(4)));
typedef __bf16 bf16x8 __attribute__((ext_vector_type(8)));

__device__ __forceinline__ unsigned short f2bf(float f) {
  union { float f; unsigned u; } v; v.f = f;
  unsigned r = v.u + 0x7FFFu + ((v.u >> 16) & 1u);
  return (unsigned short)(r >> 16);
}
__device__ __forceinline__ float sigmoidf_(float x) { return 1.f / (1.f + __expf(-x)); }
__device__ __forceinline__ float tanh_fast(float x) {
  float ax = fabsf(x);
  float e = __expf(ax + ax);
  float t = 1.f - 2.f / (e + 1.f);
  return copysignf(t, x);
}

// System-scope exchange (sc0 sc1): proven r2/r3/r5 path via memory-side
// coherence point (~0.5us per dependent op). r4 ERRATUM: sc0-only loads
// never observe remote stores on gfx950 -> do NOT use L2-scope polling.
__device__ __forceinline__ void st_u64_sys(unsigned long long* p, unsigned long long v) {
  asm volatile("global_store_dwordx2 %0, %1, off sc0 sc1" :: "v"(p), "v"(v) : "memory");
}
__device__ __forceinline__ unsigned long long ld_u64_sys(const unsigned long long* p) {
  unsigned long long a;
  asm volatile("global_load_dwordx2 %0, %1, off sc0 sc1\n\ts_waitcnt vmcnt(0)"
               : "=&v"(a) : "v"(p) : "memory");
  return a;
}

#define GLDS16(gp, lp)                                                                 \
  __builtin_amdgcn_global_load_lds((const __attribute__((address_space(1))) void*)(gp),\
                                   (__attribute__((address_space(3))) void*)(lp), 16, 0, 0)

// ---------------- fp32 -> bf16 convert (x and y fused) ----------------
__global__ void cvt_xy(const float* __restrict__ x, const float* __restrict__ y,
                       unsigned short* __restrict__ xb, unsigned short* __restrict__ yb) {
  int i = (blockIdx.x * blockDim.x + threadIdx.x) * 4;
  const float* src;
  unsigned short* dst;
  int j;
  if (i < TEnc * HID) { src = x; dst = xb; j = i; }
  else { src = y; dst = yb; j = i - TEnc * HID; }
  float4 v = *(const float4*)(src + j);
  ushort4 o;
  o.x = f2bf(v.x); o.y = f2bf(v.y); o.z = f2bf(v.z); o.w = f2bf(v.w);
  *(ushort4*)(dst + j) = o;
}

// ---------------- BT-GEMM: C[M,N] = A[M,K](bf16) * B[N,K]^T(f32->bf16) + bias ----------------
template <int BN, int BK>
__global__ __launch_bounds__(256, 1) void gemm_bt(
    const unsigned short* __restrict__ Abf, const float* __restrict__ B,
    const float* __restrict__ bias, float* __restrict__ C, unsigned short* __restrict__ Cbf,
    int M, int N, int K) {
  constexpr int NF = BN / 16;
  constexpr int B4 = BN * BK / 1024;
  constexpr int AG = BK / 16;
  constexpr int KK = BK / 32;
  extern __shared__ char smem[];
  unsigned short* Al0 = (unsigned short*)smem;
  unsigned short* Al1 = Al0 + 128 * BK;
  unsigned short* Bl0 = Al1 + 128 * BK;
  unsigned short* Bl1 = Bl0 + BN * BK;

  const int tid = threadIdx.x;
  const int lane = tid & 63;
  const int wid = tid >> 6;
  const int m0 = blockIdx.x * 128;
  const int n0 = blockIdx.y * BN;
  const int NT = K / BK;

  float4 breg[B4];
  f32x4 acc[2][NF];
#pragma unroll
  for (int i = 0; i < 2; ++i)
#pragma unroll
    for (int j = 0; j < NF; ++j) acc[i][j] = (f32x4){0.f, 0.f, 0.f, 0.f};

  auto stageA = [&](int t, unsigned short* dst) {
    const unsigned short* Ab = Abf + (size_t)m0 * K + (size_t)t * BK;
#pragma unroll
    for (int g = 0; g < AG; ++g) {
      int elem = g * 2048 + tid * 8;
      int arow = elem / BK;
      int acol = elem - arow * BK;
      GLDS16(Ab + (size_t)arow * K + acol, (char*)dst + g * 4096 + wid * 1024);
    }
  };
  auto loadB = [&](int t) {
    const float* Bb = B + (size_t)t * BK;
#pragma unroll
    for (int p = 0; p < B4; ++p) {
      int e = (p * 256 + tid) * 4;
      int brow = e / BK;
      int bcol = e - brow * BK;
      int grow = n0 + brow;
      if (grow > N - 1) grow = N - 1;
      breg[p] = *(const float4*)(Bb + (size_t)grow * K + bcol);
    }
  };
  auto writeB = [&](unsigned short* dst) {
#pragma unroll
    for (int p = 0; p < B4; ++p) {
      ushort4 o;
      o.x = f2bf(breg[p].x); o.y = f2bf(breg[p].y);
      o.z = f2bf(breg[p].z); o.w = f2bf(breg[p].w);
      *(ushort4*)((char*)dst + (p * 256 + tid) * 8) = o;
    }
  };

  stageA(0, Al0);
  loadB(0);
  for (int t = 0; t < NT; ++t) {
    unsigned short* Ac = (t & 1) ? Al1 : Al0;
    unsigned short* Bc = (t & 1) ? Bl1 : Bl0;
    asm volatile("s_waitcnt vmcnt(0)" ::: "memory");
    writeB(Bc);
    __syncthreads();
    if (t + 1 < NT) {
      stageA(t + 1, (t & 1) ? Al0 : Al1);
      loadB(t + 1);
    }
    const int r0 = lane & 15;
    const int kb = (lane >> 4) * 8;
#pragma unroll
    for (int kk = 0; kk < KK; ++kk) {
      int ko = kk * 32 + kb;
      bf16x8 a0 = *(const bf16x8*)(Ac + (wid * 32 + r0) * BK + ko);
      bf16x8 a1 = *(const bf16x8*)(Ac + (wid * 32 + 16 + r0) * BK + ko);
#pragma unroll
      for (int nf = 0; nf < NF; ++nf) {
        bf16x8 bb = *(const bf16x8*)(Bc + (nf * 16 + r0) * BK + ko);
        acc[0][nf] = __builtin_amdgcn_mfma_f32_16x16x32_bf16(a0, bb, acc[0][nf], 0, 0, 0);
        acc[1][nf] = __builtin_amdgcn_mfma_f32_16x16x32_bf16(a1, bb, acc[1][nf], 0, 0, 0);
      }
    }
  }
  const int cc = lane & 15;
  const int rq = (lane >> 4) * 4;
#pragma unroll
  for (int mi = 0; mi < 2; ++mi) {
    int row = m0 + wid * 32 + mi * 16 + rq;
#pragma unroll
    for (int nf = 0; nf < NF; ++nf) {
      int col = n0 + nf * 16 + cc;
      if (col < N) {
        float bv = bias ? bias[col] : 0.f;
#pragma unroll
        for (int j = 0; j < 4; ++j) {
          float v = acc[mi][nf][j] + bv;
          if (C) C[(size_t)(row + j) * N + col] = v;
          if (Cbf) Cbf[(size_t)(row + j) * N + col] = f2bf(v);
        }
      }
    }
  }
}

// ---------------- encoder GEMM with fused GRU gates (h_prev = 0) ----------------
__global__ __launch_bounds__(256, 1) void gemm_enc(
    const unsigned short* __restrict__ Abf, const float* __restrict__ Wi,
    const float* __restrict__ bi, const float* __restrict__ bh,
    float* __restrict__ encH, unsigned short* __restrict__ encHbf) {
  constexpr int BN = 96, BK = 128, NF = 6, B4 = 12, AG = 8, KK = 4, K = 512;
  extern __shared__ char smem[];
  unsigned short* Al0 = (unsigned short*)smem;
  unsigned short* Al1 = Al0 + 128 * BK;
  unsigned short* Bl0 = Al1 + 128 * BK;
  unsigned short* Bl1 = Bl0 + BN * BK;

  const int tid = threadIdx.x;
  const int lane = tid & 63;
  const int wid = tid >> 6;
  const int m0 = blockIdx.x * 128;
  const int n0g = blockIdx.y * 32;
  const int NT = K / BK;

  float4 breg[B4];
  f32x4 acc[2][NF];
#pragma unroll
  for (int i = 0; i < 2; ++i)
#pragma unroll
    for (int j = 0; j < NF; ++j) acc[i][j] = (f32x4){0.f, 0.f, 0.f, 0.f};

  auto stageA = [&](int t, unsigned short* dst) {
    const unsigned short* Ab = Abf + (size_t)m0 * K + (size_t)t * BK;
#pragma unroll
    for (int g = 0; g < AG; ++g) {
      int elem = g * 2048 + tid * 8;
      int arow = elem >> 7;
      int acol = elem & 127;
      GLDS16(Ab + (size_t)arow * K + acol, (char*)dst + g * 4096 + wid * 1024);
    }
  };
  auto loadB = [&](int t) {
    const float* Bb = Wi + (size_t)t * BK;
#pragma unroll
    for (int p = 0; p < B4; ++p) {
      int e = (p * 256 + tid) * 4;
      int brow = e >> 7;
      int bcol = e & 127;
      int grow = (brow >> 5) * HID + n0g + (brow & 31);
      breg[p] = *(const float4*)(Bb + (size_t)grow * K + bcol);
    }
  };
  auto writeB = [&](unsigned short* dst) {
#pragma unroll
    for (int p = 0; p < B4; ++p) {
      ushort4 o;
      o.x = f2bf(breg[p].x); o.y = f2bf(breg[p].y);
      o.z = f2bf(breg[p].z); o.w = f2bf(breg[p].w);
      *(ushort4*)((char*)dst + (p * 256 + tid) * 8) = o;
    }
  };

  stageA(0, Al0);
  loadB(0);
  for (int t = 0; t < NT; ++t) {
    unsigned short* Ac = (t & 1) ? Al1 : Al0;
    unsigned short* Bc = (t & 1) ? Bl1 : Bl0;
    asm volatile("s_waitcnt vmcnt(0)" ::: "memory");
    writeB(Bc);
    __syncthreads();
    if (t + 1 < NT) {
      stageA(t + 1, (t & 1) ? Al0 : Al1);
      loadB(t + 1);
    }
    const int r0 = lane & 15;
    const int kb = (lane >> 4) * 8;
#pragma unroll
    for (int kk = 0; kk < KK; ++kk) {
      int ko = kk * 32 + kb;
      bf16x8 a0 = *(const bf16x8*)(Ac + (wid * 32 + r0) * BK + ko);
      bf16x8 a1 = *(const bf16x8*)(Ac + (wid * 32 + 16 + r0) * BK + ko);
#pragma unroll
      for (int nf = 0; nf < NF; ++nf) {
        bf16x8 bb = *(const bf16x8*)(Bc + (nf * 16 + r0) * BK + ko);
        acc[0][nf] = __builtin_amdgcn_mfma_f32_16x16x32_bf16(a0, bb, acc[0][nf], 0, 0, 0);
        acc[1][nf] = __builtin_amdgcn_mfma_f32_16x16x32_bf16(a1, bb, acc[1][nf], 0, 0, 0);
      }
    }
  }
  const int cc = lane & 15;
  const int rq = (lane >> 4) * 4;
#pragma unroll
  for (int mi = 0; mi < 2; ++mi) {
    int row = m0 + wid * 32 + mi * 16 + rq;
#pragma unroll
    for (int nfj = 0; nfj < 2; ++nfj) {
      int j = n0g + nfj * 16 + cc;
      float br_ = bi[j] + bh[j];
      float bz_ = bi[HID + j] + bh[HID + j];
      float bin_ = bi[2 * HID + j];
      float bhn_ = bh[2 * HID + j];
#pragma unroll
      for (int jj = 0; jj < 4; ++jj) {
        float r = sigmoidf_(acc[mi][nfj][jj] + br_);
        float z = sigmoidf_(acc[mi][nfj + 2][jj] + bz_);
        float n = tanh_fast(acc[mi][nfj + 4][jj] + bin_ + r * bhn_);
        float h = (1.f - z) * n;
        encH[(size_t)(row + jj) * HID + j] = h;
        encHbf[(size_t)(row + jj) * HID + j] = f2bf(h);
      }
    }
  }
}

// ---------------- sequential GRU scan: 32 WGs, sys-scope tagged exchange ----------------
// Grid = exactly 32 WGs (always co-resident on 256 CUs; no election needed
// since exchange is system-scope regardless of XCD placement). Weights
// reg-resident (96KB fp32/WG). Exchange: 256 u64 words, each (tag<<32 |
// 2x bf16 h-dims), double-buffered by t&1; every thread polls ONE word.
// Own-dim recurrence stays fp32 in wave3's hreg.
__global__ __launch_bounds__(256, 1) void gru_scan(
    const float* __restrict__ Whd, const float* __restrict__ bhd,
    const float* __restrict__ giY, const float* __restrict__ h0,
    unsigned long long* __restrict__ hx,
    unsigned short* __restrict__ decSbf, unsigned short* __restrict__ concatbf) {
  __shared__ float hl[548];   // word w -> slot w + ((w>>7)<<2); 544 used
  __shared__ float dots[48];
  const int tid = threadIdx.x;
  const int lane = tid & 63, wid = tid >> 6;
  const int g = blockIdx.x;

  const int row16 = lane & 15;
  const int q = lane >> 4;
  // weights into registers: lane holds W[wrow*512 + g*16 + row16][q*128..+127]
  float4 wreg[32];
  {
    int wrow = (wid < 3) ? wid : 0;
    const float* wr = Whd + ((size_t)wrow * HID + (size_t)g * 16 + row16) * HID + q * 128;
#pragma unroll
    for (int i = 0; i < 32; ++i) wreg[i] = *(const float4*)(wr + i * 4);
  }
  float bhr = 0.f, bhz = 0.f, bhn = 0.f, hreg = 0.f;
  if (wid == 3 && lane < 16) {
    int jj = g * 16 + lane;
    bhr = bhd[jj]; bhz = bhd[HID + jj]; bhn = bhd[2 * HID + jj];
    hreg = h0[jj];
  }
  {
    int w0 = tid * 2, w1 = tid * 2 + 1;
    hl[w0 + ((w0 >> 7) << 2)] = h0[w0];
    hl[w1 + ((w1 >> 7) << 2)] = h0[w1];
  }
  __syncthreads();

  for (int t = 0; t < TDec; ++t) {
    float gir = 0.f, giz = 0.f, gin = 0.f;
    if (wid < 3) {
      const float4* hp = (const float4*)hl;
      const int hb = q * 33;
      float p0 = 0.f, p1 = 0.f, p2 = 0.f, p3 = 0.f;
#pragma unroll
      for (int i = 0; i < 32; i += 4) {
        float4 ha = hp[hb + i], hv = hp[hb + i + 1], hc = hp[hb + i + 2], hd = hp[hb + i + 3];
        float4 wa = wreg[i], wb = wreg[i + 1], wc = wreg[i + 2], wd = wreg[i + 3];
        p0 += wa.x * ha.x + wa.y * ha.y + wa.z * ha.z + wa.w * ha.w;
        p1 += wb.x * hv.x + wb.y * hv.y + wb.z * hv.z + wb.w * hv.w;
        p2 += wc.x * hc.x + wc.y * hc.y + wc.z * hc.z + wc.w * hc.w;
        p3 += wd.x * hd.x + wd.y * hd.y + wd.z * hd.z + wd.w * hd.w;
      }
      float p = (p0 + p1) + (p2 + p3);
      p += __shfl_xor(p, 16);
      p += __shfl_xor(p, 32);
      if (lane < 16) dots[wid * 16 + lane] = p;
    } else if (lane < 16) {
      int jj = g * 16 + lane;
      const float* gi = giY + (size_t)t * THREE_H;
      gir = gi[jj]; giz = gi[HID + jj]; gin = gi[2 * HID + jj];  // hidden under dots
    }
    __syncthreads();  // dots ready; hl(t) reads done
    unsigned long long* hxB = hx + (size_t)(t & 1) * 256;
    if (wid == 3 && lane < 16) {
      int jj = g * 16 + lane;
      float r = sigmoidf_(gir + dots[lane] + bhr);
      float z = sigmoidf_(giz + dots[16 + lane] + bhz);
      float n = tanh_fast(gin + r * (dots[32 + lane] + bhn));
      float hn = (1.f - z) * n + z * hreg;
      hreg = hn;
      unsigned short hb16 = f2bf(hn);
      unsigned short hb_up = (unsigned short)__shfl_xor((int)hb16, 1);
      if ((lane & 1) == 0) {
        unsigned long long w = ((unsigned long long)(unsigned)(t + 1) << 32) |
                               ((unsigned)hb_up << 16) | (unsigned)hb16;
        st_u64_sys(hxB + g * 8 + (lane >> 1), w);
      }
      decSbf[(size_t)t * HID + jj] = hb16;
      concatbf[(size_t)t * 2 * HID + HID + jj] = hb16;
    }
    if (t == TDec - 1) break;
    {
      const unsigned long long* p0 = hxB + tid;
      const unsigned tag = (unsigned)(t + 1);
      unsigned long long v;
      int guard = 0;
      do { v = ld_u64_sys(p0); } while ((unsigned)(v >> 32) != tag && ++guard < (1 << 20));
      int w0 = tid * 2, w1 = tid * 2 + 1;
      hl[w0 + ((w0 >> 7) << 2)] = __uint_as_float(((unsigned)v & 0xFFFFu) << 16);
      hl[w1 + ((w1 >> 7) << 2)] = __uint_as_float((((unsigned)v >> 16) & 0xFFFFu) << 16);
    }
    __syncthreads();
  }
}

// ---------------- attention scores + softmax + context ----------------
__global__ __launch_bounds__(256) void attn_ctx(const float* __restrict__ encP,
                                                const float* __restrict__ decP,
                                                const float* __restrict__ vattn,
                                                const float* __restrict__ encH,
                                                unsigned short* __restrict__ concatbf) {
  __shared__ float dp[ADIM], vv[ADIM], pl[TEnc];
  __shared__ float red[8];
  const int t = blockIdx.x, tid = threadIdx.x;
  if (tid < 64) {
    *(float4*)(dp + tid * 4) = *(const float4*)(decP + (size_t)t * ADIM + tid * 4);
    *(float4*)(vv + tid * 4) = *(const float4*)(vattn + tid * 4);
  }
  __syncthreads();
  float s = 0.f;
  const float* ep = encP + (size_t)tid * ADIM;
#pragma unroll 4
  for (int a = 0; a < ADIM; a += 4) {
    float4 e4 = *(const float4*)(ep + a);
    s += vv[a] * tanh_fast(e4.x + dp[a]);
    s += vv[a + 1] * tanh_fast(e4.y + dp[a + 1]);
    s += vv[a + 2] * tanh_fast(e4.z + dp[a + 2]);
    s += vv[a + 3] * tanh_fast(e4.w + dp[a + 3]);
  }
  float m = s;
#pragma unroll
  for (int off = 32; off; off >>= 1) m = fmaxf(m, __shfl_xor(m, off));
  if ((tid & 63) == 0) red[tid >> 6] = m;
  __syncthreads();
  m = fmaxf(fmaxf(red[0], red[1]), fmaxf(red[2], red[3]));
  float p = __expf(s - m);
  pl[tid] = p;
  float sum = p;
#pragma unroll
  for (int off = 32; off; off >>= 1) sum += __shfl_xor(sum, off);
  if ((tid & 63) == 0) red[4 + (tid >> 6)] = sum;
  __syncthreads();
  float inv = 1.f / (red[4] + red[5] + red[6] + red[7]);
  float a0 = 0.f, a1 = 0.f;
  for (int e = 0; e < TEnc; ++e) {
    float pe = pl[e];
    a0 += pe * encH[(size_t)e * HID + tid];
    a1 += pe * encH[(size_t)e * HID + tid + 256];
  }
  concatbf[(size_t)t * 2 * HID + tid] = f2bf(a0 * inv);
  concatbf[(size_t)t * 2 * HID + tid + 256] = f2bf(a1 * inv);
}

extern "C" void kernel_launch(void* const* d_in, const int* in_sizes, int n_in,
                              void* d_out, int out_size, void* d_ws, size_t ws_size,
                              hipStream_t stream) {
  const float* x = (const float*)d_in[0];
  const float* y = (const float*)d_in[1];
  const float* Wi_e = (const float*)d_in[2];
  const float* bi_e = (const float*)d_in[4];
  const float* bh_e = (const float*)d_in[5];
  const float* Wi_d = (const float*)d_in[6];
  const float* Wh_d = (const float*)d_in[7];
  const float* bi_d = (const float*)d_in[8];
  const float* bh_d = (const float*)d_in[9];
  const float* Wh_attn = (const float*)d_in[10];
  const float* Ws_attn = (const float*)d_in[11];
  const float* b_attn = (const float*)d_in[12];
  const float* v_attn = (const float*)d_in[13];
  const float* W1 = (const float*)d_in[14];
  const float* b1 = (const float*)d_in[15];
  const float* W2 = (const float*)d_in[16];
  const float* b2 = (const float*)d_in[17];
  float* out = (float*)d_out;

  char* ws = (char*)d_ws;
  size_t off = 0;
  auto alloc = [&](size_t bytes) {
    char* p = ws + off;
    off += (bytes + 255) & ~(size_t)255;
    return p;
  };
  char* ctrl = alloc(4096);
  unsigned long long* hx = (unsigned long long*)ctrl;  // 2*256*8 = 4096
  unsigned short* Xbf = (unsigned short*)alloc((size_t)TEnc * HID * 2);
  unsigned short* Ybf = (unsigned short*)alloc((size_t)TDec * HID * 2);
  float* giY = (float*)alloc((size_t)TDec * THREE_H * 4);
  float* encH = (float*)alloc((size_t)TEnc * HID * 4);
  unsigned short* encHbf = (unsigned short*)alloc((size_t)TEnc * HID * 2);
  float* encP = (float*)alloc((size_t)TEnc * ADIM * 4);
  float* decP = (float*)alloc((size_t)TDec * ADIM * 4);
  unsigned short* decSbf = (unsigned short*)alloc((size_t)TDec * HID * 2);
  unsigned short* concatbf = (unsigned short*)alloc((size_t)TDec * 2 * HID * 2);
  unsigned short* out1bf = (unsigned short*)alloc((size_t)TDec * 20000 * 2);

  hipMemsetAsync(ctrl, 0, 4096, stream);  // zero exchange tags every launch

  auto* g32 = gemm_bt<32, 128>;
  auto* g80 = gemm_bt<80, 128>;
  auto* g64 = gemm_bt<64, 160>;
  const int smem32 = (128 + 32) * 128 * 2 * 2;      // 81920
  const int smem80 = (128 + 80) * 128 * 2 * 2;      // 106496
  const int smem64 = (128 + 64) * 160 * 2 * 2;      // 122880
  const int smemEnc = (128 + 96) * 128 * 2 * 2;     // 114688
  hipFuncSetAttribute((const void*)g32, hipFuncAttributeMaxDynamicSharedMemorySize, smem32);
  hipFuncSetAttribute((const void*)g80, hipFuncAttributeMaxDynamicSharedMemorySize, smem80);
  hipFuncSetAttribute((const void*)g64, hipFuncAttributeMaxDynamicSharedMemorySize, smem64);
  hipFuncSetAttribute((const void*)gemm_enc, hipFuncAttributeMaxDynamicSharedMemorySize, smemEnc);

  cvt_xy<<<(TEnc + TDec) * HID / 1024, 256, 0, stream>>>(x, y, Xbf, Ybf);
  // encoder GEMM + fused gates
  gemm_enc<<<dim3(2, 16), 256, smemEnc, stream>>>(Xbf, Wi_e, bi_e, bh_e, encH, encHbf);
  // encP = encH @ Wh_attn^T
  g32<<<dim3(2, 8), 256, smem32, stream>>>(encHbf, Wh_attn, nullptr, encP, nullptr, 256, 256, 512);
  // giY = Ybf @ Wi_d^T + bi_d
  g32<<<dim3(1, 48), 256, smem32, stream>>>(Ybf, Wi_d, bi_d, giY, nullptr, 128, 1536, 512);
  // sequential decoder: 32-WG sys-scope exchange scan
  gru_scan<<<32, 256, 0, stream>>>(Wh_d, bh_d, giY, encH + 255 * HID, hx, decSbf, concatbf);
  // decP = decS @ Ws_attn^T + b_attn
  g32<<<dim3(1, 8), 256, smem32, stream>>>(decSbf, Ws_attn, b_attn, decP, nullptr, 128, 256, 512);
  attn_ctx<<<TDec, 256, 0, stream>>>(encP, decP, v_attn, encH, concatbf);
  // out1 = concat @ W1^T + b1 (store bf16)
  g80<<<dim3(1, 250), 256, smem80, stream>>>(concatbf, W1, b1, nullptr, out1bf, 128, 20000, 1024);
  // out = out1 @ W2^T + b2 (f32 B-stream, 800MB once)
  g64<<<dim3(1, 157), 256, smem64, stream>>>(out1bf, W2, b2, out, nullptr, 128, NVOC, 20000);
}